// Round 11
// baseline (145.424 us; speedup 1.0000x reference)
//
#include <hip/hip_runtime.h>

#define N_PTS 1000000
#define KC 64
#define DD 8
#define NPAIR 36          // D*(D+1)/2
#define COEF_STRIDE 48    // general-path: 36 quad + 8 linear + 1 const + 3 pad
#define FAST_STRIDE 16    // fast-path: 8 linear + 1 const + 7 pad (64 B)
#define BLK 256
#define PT_PER_TH 4
#define PTS_PER_BLK (BLK * PT_PER_TH)
#define NB ((N_PTS + PTS_PER_BLK - 1) / PTS_PER_BLK)

#if __has_builtin(__builtin_amdgcn_exp2f)
#define EXP2F(x) __builtin_amdgcn_exp2f(x)
#else
#define EXP2F(x) exp2f(x)
#endif
#if __has_builtin(__builtin_amdgcn_logf)
#define LOG2F_FAST(x) __builtin_amdgcn_logf(x)
#else
#define LOG2F_FAST(x) log2f(x)
#endif
#if __has_builtin(__builtin_amdgcn_rcpf)
#define RCPF(x) __builtin_amdgcn_rcpf(x)
#else
#define RCPF(x) (1.0f / (x))
#endif
#if __has_builtin(__builtin_amdgcn_sqrtf)
#define SQRTF(x) __builtin_amdgcn_sqrtf(x)
#else
#define SQRTF(x) sqrtf(x)
#endif

#define LOG2E 1.44269504088896340736f
#define LN2F  0.69314718055994530942f
#define LN2PI 1.83787706640934548356f

__device__ __forceinline__ float fast_tanh(float x) {
    float cl = fminf(fmaxf(x, -15.f), 15.f);
    float e = EXP2F(cl * (2.f * LOG2E));      // e^(2x)
    return (e - 1.f) * RCPF(e + 1.f);
}

// ---------------------------------------------------------------------------
// Prep: one thread per component (1 wave). Fully unrolled (rule #20). Emits:
//   coefs[K][48]  full per-k affine form (general path, LDS-staged)
//   fastc[K][16]  compact {V[8], C} for the shared-quadratic fast path
//   flag          1 iff the quadratic block W is bitwise-identical across k
// ---------------------------------------------------------------------------
__global__ __launch_bounds__(64, 1) void gmm_prep(
    const float* __restrict__ prior_logits,
    const float* __restrict__ mus,
    const float* __restrict__ cov_raw,
    float* __restrict__ coefs,
    float* __restrict__ fastc,
    double* __restrict__ acc,
    int* __restrict__ counter,
    int* __restrict__ flag)
{
    const int k = threadIdx.x;
    if (k == 0) { *acc = 0.0; *counter = 0; }

    const float* raw = cov_raw + k * DD * DD;
    float A[DD][DD];
    #pragma unroll
    for (int i = 0; i < DD; ++i)
        #pragma unroll
        for (int j = 0; j < DD; ++j)
            A[i][j] = (i == j) ? EXP2F(raw[i * DD + i] * LOG2E)
                               : fast_tanh(0.5f * (raw[i * DD + j] + raw[j * DD + i]));

    // Cholesky A = L L^T
    float L[DD][DD], Dinv[DD];
    float ld2 = 0.f;  // log2(det)
    #pragma unroll
    for (int j = 0; j < DD; ++j) {
        float s = A[j][j];
        #pragma unroll
        for (int t = 0; t < j; ++t) s -= L[j][t] * L[j][t];
        float ljj = SQRTF(s);
        L[j][j] = ljj;
        float rinv = RCPF(ljj);
        Dinv[j] = rinv;
        ld2 += 2.f * LOG2F_FAST(ljj);
        #pragma unroll
        for (int i = j + 1; i < DD; ++i) {
            float v = A[i][j];
            #pragma unroll
            for (int t = 0; t < j; ++t) v -= L[i][t] * L[j][t];
            L[i][j] = v * rinv;
        }
    }

    // Sinv = A^{-1} column by column (all unrolled -> registers)
    float Sinv[DD][DD];
    #pragma unroll
    for (int c = 0; c < DD; ++c) {
        float y[DD], z[DD];
        #pragma unroll
        for (int i = 0; i < DD; ++i) {
            float v = (i == c) ? 1.f : 0.f;
            #pragma unroll
            for (int t = 0; t < i; ++t) v -= L[i][t] * y[t];
            y[i] = v * Dinv[i];
        }
        #pragma unroll
        for (int i = DD - 1; i >= 0; --i) {
            float v = y[i];
            #pragma unroll
            for (int t = i + 1; t < DD; ++t) v -= L[t][i] * z[t];
            z[i] = v * Dinv[i];
        }
        #pragma unroll
        for (int i = 0; i < DD; ++i) Sinv[i][c] = z[i];
    }

    const float* mu = mus + k * DD;
    float smu[DD];
    float cc = 0.f;
    #pragma unroll
    for (int i = 0; i < DD; ++i) {
        float v = 0.f;
        #pragma unroll
        for (int j = 0; j < DD; ++j) v += Sinv[i][j] * mu[j];
        smu[i] = v;
        cc += mu[i] * v;
    }

    // wave-parallel softmax(prior_logits)[k]
    float lg = prior_logits[k];
    float m = lg;
    #pragma unroll
    for (int off = 32; off > 0; off >>= 1)
        m = fmaxf(m, __shfl_xor(m, off, 64));
    float e = EXP2F((lg - m) * LOG2E);
    float se = e;
    #pragma unroll
    for (int off = 32; off > 0; off >>= 1)
        se += __shfl_xor(se, off, 64);
    float lprior = lg - m - LOG2F_FAST(se) * LN2F;

    const float s2 = -0.5f * LOG2E;
    float qw[NPAIR];
    {
        int t = 0;
        #pragma unroll
        for (int i = 0; i < DD; ++i)
            #pragma unroll
            for (int j = i; j < DD; ++j) {
                qw[t] = s2 * Sinv[i][j] * ((i == j) ? 1.f : 2.f);
                ++t;
            }
    }
    const float cconst = LOG2E * (lprior - 4.f * LN2PI) + s2 * (ld2 * LN2F + cc);

    float* w = coefs + k * COEF_STRIDE;
    #pragma unroll
    for (int t = 0; t < NPAIR; ++t) w[t] = qw[t];
    #pragma unroll
    for (int i = 0; i < DD; ++i) w[NPAIR + i] = LOG2E * smu[i];
    w[44] = cconst;
    w[45] = 0.f; w[46] = 0.f; w[47] = 0.f;

    // compact fast-path record (64 B stride)
    float* f = fastc + k * FAST_STRIDE;
    #pragma unroll
    for (int i = 0; i < DD; ++i) f[i] = LOG2E * smu[i];
    f[8] = cconst;
    #pragma unroll
    for (int i = 9; i < FAST_STRIDE; ++i) f[i] = 0.f;

    // all-k quad-block equality check (bitwise; NaN -> flag 0 -> general path)
    int eq = 1;
    #pragma unroll
    for (int t = 0; t < NPAIR; ++t) {
        float l0v = __shfl(qw[t], 0, 64);
        eq &= (qw[t] == l0v) ? 1 : 0;
    }
    unsigned long long b = __ballot(eq != 0);
    if (k == 0) *flag = (b == 0xFFFFFFFFFFFFFFFFULL) ? 1 : 0;
}

// ---------------------------------------------------------------------------
// Main, 4 points/thread.
// Fast path: shared quadratic + per-k {V[8],C} via the SCALAR pipe, with an
// EXPLICIT one-iteration register software-pipeline: k+1's coef loads are
// issued before k's 40-FMA/exp2 block (R10 showed the compiler does NOT
// pipeline the loads itself -> full load latency per k, VALUBusy ~40%).
// Fully unrolled so the rotation is pure SSA renaming.
// General path (flag=0): LDS-staged per-k full quadratic (fallback).
// ---------------------------------------------------------------------------
__global__ __launch_bounds__(BLK) void gmm_main(
    const float* __restrict__ X,
    const float* __restrict__ coefs,
    const float* __restrict__ fastc,
    const int* __restrict__ flag,
    double* __restrict__ acc,
    int* __restrict__ counter,
    float* __restrict__ out)
{
    __shared__ float4 lcoef[KC * 12];   // used by general path only

    const int pbase = blockIdx.x * PTS_PER_BLK + threadIdx.x;

    float x[PT_PER_TH][DD];
    bool  valid[PT_PER_TH];
    #pragma unroll
    for (int p = 0; p < PT_PER_TH; ++p) {
        const int pi = pbase + p * BLK;
        valid[p] = (pi < N_PTS);
        if (valid[p]) {
            const float4* xp = (const float4*)(X + (size_t)pi * DD);
            float4 a = xp[0], b = xp[1];
            x[p][0]=a.x; x[p][1]=a.y; x[p][2]=a.z; x[p][3]=a.w;
            x[p][4]=b.x; x[p][5]=b.y; x[p][6]=b.z; x[p][7]=b.w;
        } else {
            #pragma unroll
            for (int i = 0; i < DD; ++i) x[p][i] = 0.f;
        }
    }

    double ll = 0.0;

    if (*flag) {
        // ---- fast path ----
        float q[PT_PER_TH];
        {
            float Q[NPAIR];
            #pragma unroll
            for (int t = 0; t < NPAIR; ++t) Q[t] = coefs[t];   // uniform -> s_load
            #pragma unroll
            for (int p = 0; p < PT_PER_TH; ++p) {
                float qq = 0.f;
                int t = 0;
                #pragma unroll
                for (int i = 0; i < DD; ++i) {
                    float s = 0.f;
                    #pragma unroll
                    for (int j = i; j < DD; ++j, ++t)
                        s = fmaf(Q[t], x[p][j], s);
                    qq = fmaf(x[p][i], s, qq);
                }
                q[p] = qq;
            }
        }

        float ss[PT_PER_TH];
        #pragma unroll
        for (int p = 0; p < PT_PER_TH; ++p) ss[p] = 0.f;

        const float4* fc4 = (const float4*)fastc;   // 4 float4 per k
        // software pipeline: preload k=0, then {issue k+1 loads; compute k}
        float4 ca = fc4[0];
        float4 cb = fc4[1];
        float4 cd = fc4[2];      // .x = const
        #pragma unroll
        for (int k = 0; k < KC; ++k) {
            float4 na, nb, nd;
            if (k + 1 < KC) {                 // static under full unroll
                na = fc4[(k + 1) * 4 + 0];
                nb = fc4[(k + 1) * 4 + 1];
                nd = fc4[(k + 1) * 4 + 2];
            }
            #pragma unroll
            for (int p = 0; p < PT_PER_TH; ++p) {
                float a = fmaf(ca.x, x[p][0], cd.x);
                a = fmaf(ca.y, x[p][1], a);
                a = fmaf(ca.z, x[p][2], a);
                a = fmaf(ca.w, x[p][3], a);
                a = fmaf(cb.x, x[p][4], a);
                a = fmaf(cb.y, x[p][5], a);
                a = fmaf(cb.z, x[p][6], a);
                a = fmaf(cb.w, x[p][7], a);
                ss[p] += EXP2F(a);
            }
            if (k + 1 < KC) { ca = na; cb = nb; cd = nd; }
        }

        #pragma unroll
        for (int p = 0; p < PT_PER_TH; ++p)
            if (valid[p])
                ll += (double)((q[p] + LOG2F_FAST(ss[p])) * LN2F);
    } else {
        // ---- general path: LDS-staged per-k full quadratic ----
        {
            const float4* g = (const float4*)coefs;
            #pragma unroll
            for (int r = 0; r < 3; ++r)
                lcoef[threadIdx.x + r * BLK] = g[threadIdx.x + r * BLK];
        }
        __syncthreads();

        float ss[PT_PER_TH];
        #pragma unroll
        for (int p = 0; p < PT_PER_TH; ++p) ss[p] = 0.f;

        for (int k = 0; k < KC; ++k) {
            float cw[COEF_STRIDE];
            {
                const float4* cp = &lcoef[k * 12];
                #pragma unroll
                for (int r = 0; r < 12; ++r) {
                    float4 c = cp[r];
                    cw[4*r+0] = c.x; cw[4*r+1] = c.y; cw[4*r+2] = c.z; cw[4*r+3] = c.w;
                }
            }
            #pragma unroll
            for (int p = 0; p < PT_PER_TH; ++p) {
                float a = cw[44];
                int t = 0;
                #pragma unroll
                for (int i = 0; i < DD; ++i) {
                    float s = cw[NPAIR + i];
                    #pragma unroll
                    for (int j = i; j < DD; ++j, ++t)
                        s = fmaf(cw[t], x[p][j], s);
                    a = fmaf(x[p][i], s, a);
                }
                ss[p] += EXP2F(a);
            }
        }

        #pragma unroll
        for (int p = 0; p < PT_PER_TH; ++p)
            if (valid[p])
                ll += (double)(LOG2F_FAST(ss[p]) * LN2F);
    }

    // wave(64) shuffle reduce in double
    #pragma unroll
    for (int off = 32; off > 0; off >>= 1)
        ll += __shfl_down(ll, off, 64);

    __shared__ double wsum[BLK / 64];
    const int lane = threadIdx.x & 63;
    const int wid  = threadIdx.x >> 6;
    if (lane == 0) wsum[wid] = ll;
    __syncthreads();
    if (threadIdx.x == 0) {
        double t = 0.0;
        #pragma unroll
        for (int wgi = 0; wgi < BLK / 64; ++wgi) t += wsum[wgi];
        atomicAdd(acc, t);
        __threadfence();
        int old = atomicAdd(counter, 1);
        if (old == NB - 1) {
            __threadfence();
            double v = atomicAdd(acc, 0.0);   // coherent read of the full sum
            out[0] = (float)v;
        }
    }
}

extern "C" void kernel_launch(void* const* d_in, const int* in_sizes, int n_in,
                              void* d_out, int out_size, void* d_ws, size_t ws_size,
                              hipStream_t stream)
{
    const float* X      = (const float*)d_in[0];
    const float* prior  = (const float*)d_in[1];
    const float* mus    = (const float*)d_in[2];
    const float* covraw = (const float*)d_in[3];
    float* out = (float*)d_out;

    double* acc  = (double*)d_ws;
    int* counter = (int*)((char*)d_ws + 128);
    int* flag    = (int*)((char*)d_ws + 132);
    float* coefs = (float*)((char*)d_ws + 256);                  // KC*48*4 = 12288 B
    float* fastc = (float*)((char*)d_ws + 256 + 12544);          // KC*16*4 = 4096 B

    gmm_prep<<<1, 64, 0, stream>>>(prior, mus, covraw, coefs, fastc, acc, counter, flag);
    gmm_main<<<NB, BLK, 0, stream>>>(X, coefs, fastc, flag, acc, counter, out);
}

// Round 12
// 114.246 us; speedup vs baseline: 1.2729x; 1.2729x over previous
//
#include <hip/hip_runtime.h>

#define N_PTS 1000000
#define KC 64
#define DD 8
#define NPAIR 36          // D*(D+1)/2
#define COEF_STRIDE 48    // general-path: 36 quad + 8 linear + 1 const + 3 pad
#define FAST_STRIDE 16    // fast-path: 8 linear + 1 const + 7 pad (64 B)
#define BLK 256
#define PT_PER_TH 4
#define PTS_PER_BLK (BLK * PT_PER_TH)
#define NB ((N_PTS + PTS_PER_BLK - 1) / PTS_PER_BLK)

#if __has_builtin(__builtin_amdgcn_exp2f)
#define EXP2F(x) __builtin_amdgcn_exp2f(x)
#else
#define EXP2F(x) exp2f(x)
#endif
#if __has_builtin(__builtin_amdgcn_logf)
#define LOG2F_FAST(x) __builtin_amdgcn_logf(x)
#else
#define LOG2F_FAST(x) log2f(x)
#endif
#if __has_builtin(__builtin_amdgcn_rcpf)
#define RCPF(x) __builtin_amdgcn_rcpf(x)
#else
#define RCPF(x) (1.0f / (x))
#endif
#if __has_builtin(__builtin_amdgcn_sqrtf)
#define SQRTF(x) __builtin_amdgcn_sqrtf(x)
#else
#define SQRTF(x) sqrtf(x)
#endif

#define LOG2E 1.44269504088896340736f
#define LN2F  0.69314718055994530942f
#define LN2PI 1.83787706640934548356f

// lane-broadcast via register file: no LDS, no VMEM, no waitcnt
__device__ __forceinline__ float RL(float v, int lane) {
    return __int_as_float(__builtin_amdgcn_readlane(__float_as_int(v), lane));
}

__device__ __forceinline__ float fast_tanh(float x) {
    float cl = fminf(fmaxf(x, -15.f), 15.f);
    float e = EXP2F(cl * (2.f * LOG2E));      // e^(2x)
    return (e - 1.f) * RCPF(e + 1.f);
}

// ---------------------------------------------------------------------------
// Prep: one thread per component (1 wave). Fully unrolled (rule #20). Emits:
//   coefs[K][48]  full per-k affine form (general path, LDS-staged)
//   fastc[K][16]  compact {V[8], C} for the shared-quadratic fast path
//   flag          1 iff the quadratic block W is bitwise-identical across k
// ---------------------------------------------------------------------------
__global__ __launch_bounds__(64, 1) void gmm_prep(
    const float* __restrict__ prior_logits,
    const float* __restrict__ mus,
    const float* __restrict__ cov_raw,
    float* __restrict__ coefs,
    float* __restrict__ fastc,
    double* __restrict__ acc,
    int* __restrict__ counter,
    int* __restrict__ flag)
{
    const int k = threadIdx.x;
    if (k == 0) { *acc = 0.0; *counter = 0; }

    const float* raw = cov_raw + k * DD * DD;
    float A[DD][DD];
    #pragma unroll
    for (int i = 0; i < DD; ++i)
        #pragma unroll
        for (int j = 0; j < DD; ++j)
            A[i][j] = (i == j) ? EXP2F(raw[i * DD + i] * LOG2E)
                               : fast_tanh(0.5f * (raw[i * DD + j] + raw[j * DD + i]));

    // Cholesky A = L L^T
    float L[DD][DD], Dinv[DD];
    float ld2 = 0.f;  // log2(det)
    #pragma unroll
    for (int j = 0; j < DD; ++j) {
        float s = A[j][j];
        #pragma unroll
        for (int t = 0; t < j; ++t) s -= L[j][t] * L[j][t];
        float ljj = SQRTF(s);
        L[j][j] = ljj;
        float rinv = RCPF(ljj);
        Dinv[j] = rinv;
        ld2 += 2.f * LOG2F_FAST(ljj);
        #pragma unroll
        for (int i = j + 1; i < DD; ++i) {
            float v = A[i][j];
            #pragma unroll
            for (int t = 0; t < j; ++t) v -= L[i][t] * L[j][t];
            L[i][j] = v * rinv;
        }
    }

    // Sinv = A^{-1} column by column (all unrolled -> registers)
    float Sinv[DD][DD];
    #pragma unroll
    for (int c = 0; c < DD; ++c) {
        float y[DD], z[DD];
        #pragma unroll
        for (int i = 0; i < DD; ++i) {
            float v = (i == c) ? 1.f : 0.f;
            #pragma unroll
            for (int t = 0; t < i; ++t) v -= L[i][t] * y[t];
            y[i] = v * Dinv[i];
        }
        #pragma unroll
        for (int i = DD - 1; i >= 0; --i) {
            float v = y[i];
            #pragma unroll
            for (int t = i + 1; t < DD; ++t) v -= L[t][i] * z[t];
            z[i] = v * Dinv[i];
        }
        #pragma unroll
        for (int i = 0; i < DD; ++i) Sinv[i][c] = z[i];
    }

    const float* mu = mus + k * DD;
    float smu[DD];
    float cc = 0.f;
    #pragma unroll
    for (int i = 0; i < DD; ++i) {
        float v = 0.f;
        #pragma unroll
        for (int j = 0; j < DD; ++j) v += Sinv[i][j] * mu[j];
        smu[i] = v;
        cc += mu[i] * v;
    }

    // wave-parallel softmax(prior_logits)[k]
    float lg = prior_logits[k];
    float m = lg;
    #pragma unroll
    for (int off = 32; off > 0; off >>= 1)
        m = fmaxf(m, __shfl_xor(m, off, 64));
    float e = EXP2F((lg - m) * LOG2E);
    float se = e;
    #pragma unroll
    for (int off = 32; off > 0; off >>= 1)
        se += __shfl_xor(se, off, 64);
    float lprior = lg - m - LOG2F_FAST(se) * LN2F;

    const float s2 = -0.5f * LOG2E;
    float qw[NPAIR];
    {
        int t = 0;
        #pragma unroll
        for (int i = 0; i < DD; ++i)
            #pragma unroll
            for (int j = i; j < DD; ++j) {
                qw[t] = s2 * Sinv[i][j] * ((i == j) ? 1.f : 2.f);
                ++t;
            }
    }
    const float cconst = LOG2E * (lprior - 4.f * LN2PI) + s2 * (ld2 * LN2F + cc);

    float* w = coefs + k * COEF_STRIDE;
    #pragma unroll
    for (int t = 0; t < NPAIR; ++t) w[t] = qw[t];
    #pragma unroll
    for (int i = 0; i < DD; ++i) w[NPAIR + i] = LOG2E * smu[i];
    w[44] = cconst;
    w[45] = 0.f; w[46] = 0.f; w[47] = 0.f;

    // compact fast-path record (64 B stride)
    float* f = fastc + k * FAST_STRIDE;
    #pragma unroll
    for (int i = 0; i < DD; ++i) f[i] = LOG2E * smu[i];
    f[8] = cconst;
    #pragma unroll
    for (int i = 9; i < FAST_STRIDE; ++i) f[i] = 0.f;

    // all-k quad-block equality check (bitwise; NaN -> flag 0 -> general path)
    int eq = 1;
    #pragma unroll
    for (int t = 0; t < NPAIR; ++t) {
        float l0v = __shfl(qw[t], 0, 64);
        eq &= (qw[t] == l0v) ? 1 : 0;
    }
    unsigned long long b = __ballot(eq != 0);
    if (k == 0) *flag = (b == 0xFFFFFFFFFFFFFFFFULL) ? 1 : 0;
}

// ---------------------------------------------------------------------------
// Main, 4 points/thread.
// Fast path: ZERO memory ops in the k-loop. The 64 fast-path records
// {V[8],C} live in the wave's own VGPRs, one component per lane (9 regs);
// per k the 9 values are broadcast with v_readlane (register-file cross-lane,
// no LDS/VMEM/K$ latency, no waitcnt). R9~R10 equality showed the k-loop was
// load-latency-bound (per-iter load->use ~120cyc vs ~104cyc issue, VALUBusy
// ~40-55%); this removes the latency term for +9 readlanes/k issue cost.
// General path (flag=0): LDS-staged per-k full quadratic (fallback).
// ---------------------------------------------------------------------------
__global__ __launch_bounds__(BLK) void gmm_main(
    const float* __restrict__ X,
    const float* __restrict__ coefs,
    const float* __restrict__ fastc,
    const int* __restrict__ flag,
    double* __restrict__ acc,
    int* __restrict__ counter,
    float* __restrict__ out)
{
    __shared__ float4 lcoef[KC * 12];   // used by general path only

    const int pbase = blockIdx.x * PTS_PER_BLK + threadIdx.x;

    float x[PT_PER_TH][DD];
    bool  valid[PT_PER_TH];
    #pragma unroll
    for (int p = 0; p < PT_PER_TH; ++p) {
        const int pi = pbase + p * BLK;
        valid[p] = (pi < N_PTS);
        if (valid[p]) {
            const float4* xp = (const float4*)(X + (size_t)pi * DD);
            float4 a = xp[0], b = xp[1];
            x[p][0]=a.x; x[p][1]=a.y; x[p][2]=a.z; x[p][3]=a.w;
            x[p][4]=b.x; x[p][5]=b.y; x[p][6]=b.z; x[p][7]=b.w;
        } else {
            #pragma unroll
            for (int i = 0; i < DD; ++i) x[p][i] = 0.f;
        }
    }

    double ll = 0.0;

    if (*flag) {
        // ---- fast path ----
        // lane-resident coef table: lane l holds component l's {V[8], C}
        float vk0, vk1, vk2, vk3, vk4, vk5, vk6, vk7, vk8;
        {
            const float* myrec = fastc + (threadIdx.x & 63) * FAST_STRIDE;
            vk0 = myrec[0]; vk1 = myrec[1]; vk2 = myrec[2]; vk3 = myrec[3];
            vk4 = myrec[4]; vk5 = myrec[5]; vk6 = myrec[6]; vk7 = myrec[7];
            vk8 = myrec[8];
        }

        // shared quadratic form q = x^T W x (W uniform -> s_load once)
        float q[PT_PER_TH];
        {
            float Q[NPAIR];
            #pragma unroll
            for (int t = 0; t < NPAIR; ++t) Q[t] = coefs[t];
            #pragma unroll
            for (int p = 0; p < PT_PER_TH; ++p) {
                float qq = 0.f;
                int t = 0;
                #pragma unroll
                for (int i = 0; i < DD; ++i) {
                    float s = 0.f;
                    #pragma unroll
                    for (int j = i; j < DD; ++j, ++t)
                        s = fmaf(Q[t], x[p][j], s);
                    qq = fmaf(x[p][i], s, qq);
                }
                q[p] = qq;
            }
        }

        float ss[PT_PER_TH];
        #pragma unroll
        for (int p = 0; p < PT_PER_TH; ++p) ss[p] = 0.f;

        for (int k0 = 0; k0 < KC; k0 += 8) {
            #pragma unroll
            for (int dk = 0; dk < 8; ++dk) {
                const int k = k0 + dk;
                const float c0 = RL(vk0, k), c1 = RL(vk1, k);
                const float c2 = RL(vk2, k), c3 = RL(vk3, k);
                const float c4 = RL(vk4, k), c5 = RL(vk5, k);
                const float c6 = RL(vk6, k), c7 = RL(vk7, k);
                const float c8 = RL(vk8, k);
                #pragma unroll
                for (int p = 0; p < PT_PER_TH; ++p) {
                    float a = fmaf(c0, x[p][0], c8);
                    a = fmaf(c1, x[p][1], a);
                    a = fmaf(c2, x[p][2], a);
                    a = fmaf(c3, x[p][3], a);
                    a = fmaf(c4, x[p][4], a);
                    a = fmaf(c5, x[p][5], a);
                    a = fmaf(c6, x[p][6], a);
                    a = fmaf(c7, x[p][7], a);
                    ss[p] += EXP2F(a);
                }
            }
        }

        #pragma unroll
        for (int p = 0; p < PT_PER_TH; ++p)
            if (valid[p])
                ll += (double)((q[p] + LOG2F_FAST(ss[p])) * LN2F);
    } else {
        // ---- general path: LDS-staged per-k full quadratic ----
        {
            const float4* g = (const float4*)coefs;
            #pragma unroll
            for (int r = 0; r < 3; ++r)
                lcoef[threadIdx.x + r * BLK] = g[threadIdx.x + r * BLK];
        }
        __syncthreads();

        float ss[PT_PER_TH];
        #pragma unroll
        for (int p = 0; p < PT_PER_TH; ++p) ss[p] = 0.f;

        for (int k = 0; k < KC; ++k) {
            float cw[COEF_STRIDE];
            {
                const float4* cp = &lcoef[k * 12];
                #pragma unroll
                for (int r = 0; r < 12; ++r) {
                    float4 c = cp[r];
                    cw[4*r+0] = c.x; cw[4*r+1] = c.y; cw[4*r+2] = c.z; cw[4*r+3] = c.w;
                }
            }
            #pragma unroll
            for (int p = 0; p < PT_PER_TH; ++p) {
                float a = cw[44];
                int t = 0;
                #pragma unroll
                for (int i = 0; i < DD; ++i) {
                    float s = cw[NPAIR + i];
                    #pragma unroll
                    for (int j = i; j < DD; ++j, ++t)
                        s = fmaf(cw[t], x[p][j], s);
                    a = fmaf(x[p][i], s, a);
                }
                ss[p] += EXP2F(a);
            }
        }

        #pragma unroll
        for (int p = 0; p < PT_PER_TH; ++p)
            if (valid[p])
                ll += (double)(LOG2F_FAST(ss[p]) * LN2F);
    }

    // wave(64) shuffle reduce in double
    #pragma unroll
    for (int off = 32; off > 0; off >>= 1)
        ll += __shfl_down(ll, off, 64);

    __shared__ double wsum[BLK / 64];
    const int lane = threadIdx.x & 63;
    const int wid  = threadIdx.x >> 6;
    if (lane == 0) wsum[wid] = ll;
    __syncthreads();
    if (threadIdx.x == 0) {
        double t = 0.0;
        #pragma unroll
        for (int wgi = 0; wgi < BLK / 64; ++wgi) t += wsum[wgi];
        atomicAdd(acc, t);
        __threadfence();
        int old = atomicAdd(counter, 1);
        if (old == NB - 1) {
            __threadfence();
            double v = atomicAdd(acc, 0.0);   // coherent read of the full sum
            out[0] = (float)v;
        }
    }
}

extern "C" void kernel_launch(void* const* d_in, const int* in_sizes, int n_in,
                              void* d_out, int out_size, void* d_ws, size_t ws_size,
                              hipStream_t stream)
{
    const float* X      = (const float*)d_in[0];
    const float* prior  = (const float*)d_in[1];
    const float* mus    = (const float*)d_in[2];
    const float* covraw = (const float*)d_in[3];
    float* out = (float*)d_out;

    double* acc  = (double*)d_ws;
    int* counter = (int*)((char*)d_ws + 128);
    int* flag    = (int*)((char*)d_ws + 132);
    float* coefs = (float*)((char*)d_ws + 256);                  // KC*48*4 = 12288 B
    float* fastc = (float*)((char*)d_ws + 256 + 12544);          // KC*16*4 = 4096 B

    gmm_prep<<<1, 64, 0, stream>>>(prior, mus, covraw, coefs, fastc, acc, counter, flag);
    gmm_main<<<NB, BLK, 0, stream>>>(X, coefs, fastc, flag, acc, counter, out);
}

// Round 13
// 105.421 us; speedup vs baseline: 1.3795x; 1.0837x over previous
//
#include <hip/hip_runtime.h>

#define N_PTS 1000000
#define KC 64
#define DD 8
#define NPAIR 36          // D*(D+1)/2
#define COEF_STRIDE 48    // general-path record: 36 quad + 8 linear + 1 const + 3 pad
#define FAST_STRIDE 16    // fast-path record: 8 linear + 1 const + 7 pad (64 B)
#define BLK 256
#define PT_PER_TH 8
#define PTS_PER_BLK (BLK * PT_PER_TH)
#define NB ((N_PTS + PTS_PER_BLK - 1) / PTS_PER_BLK)

#if __has_builtin(__builtin_amdgcn_exp2f)
#define EXP2F(x) __builtin_amdgcn_exp2f(x)
#else
#define EXP2F(x) exp2f(x)
#endif
#if __has_builtin(__builtin_amdgcn_logf)
#define LOG2F_FAST(x) __builtin_amdgcn_logf(x)
#else
#define LOG2F_FAST(x) log2f(x)
#endif
#if __has_builtin(__builtin_amdgcn_rcpf)
#define RCPF(x) __builtin_amdgcn_rcpf(x)
#else
#define RCPF(x) (1.0f / (x))
#endif
#if __has_builtin(__builtin_amdgcn_sqrtf)
#define SQRTF(x) __builtin_amdgcn_sqrtf(x)
#else
#define SQRTF(x) sqrtf(x)
#endif

#define LOG2E 1.44269504088896340736f
#define LN2F  0.69314718055994530942f
#define LN2PI 1.83787706640934548356f

__device__ __forceinline__ float fast_tanh(float x) {
    float cl = fminf(fmaxf(x, -15.f), 15.f);
    float e = EXP2F(cl * (2.f * LOG2E));      // e^(2x)
    return (e - 1.f) * RCPF(e + 1.f);
}

// ---------------------------------------------------------------------------
// Prep: one thread per component (1 wave). Fully unrolled (rule #20). Emits:
//   coefs[K][48]  full per-k affine form (general path)
//   fastc[K][16]  compact {V[8], C} for the shared-quadratic fast path
//   flag          1 iff the quadratic block W is bitwise-identical across k
// ---------------------------------------------------------------------------
__global__ __launch_bounds__(64, 1) void gmm_prep(
    const float* __restrict__ prior_logits,
    const float* __restrict__ mus,
    const float* __restrict__ cov_raw,
    float* __restrict__ coefs,
    float* __restrict__ fastc,
    double* __restrict__ acc,
    int* __restrict__ counter,
    int* __restrict__ flag)
{
    const int k = threadIdx.x;
    if (k == 0) { *acc = 0.0; *counter = 0; }

    const float* raw = cov_raw + k * DD * DD;
    float A[DD][DD];
    #pragma unroll
    for (int i = 0; i < DD; ++i)
        #pragma unroll
        for (int j = 0; j < DD; ++j)
            A[i][j] = (i == j) ? EXP2F(raw[i * DD + i] * LOG2E)
                               : fast_tanh(0.5f * (raw[i * DD + j] + raw[j * DD + i]));

    // Cholesky A = L L^T
    float L[DD][DD], Dinv[DD];
    float ld2 = 0.f;  // log2(det)
    #pragma unroll
    for (int j = 0; j < DD; ++j) {
        float s = A[j][j];
        #pragma unroll
        for (int t = 0; t < j; ++t) s -= L[j][t] * L[j][t];
        float ljj = SQRTF(s);
        L[j][j] = ljj;
        float rinv = RCPF(ljj);
        Dinv[j] = rinv;
        ld2 += 2.f * LOG2F_FAST(ljj);
        #pragma unroll
        for (int i = j + 1; i < DD; ++i) {
            float v = A[i][j];
            #pragma unroll
            for (int t = 0; t < j; ++t) v -= L[i][t] * L[j][t];
            L[i][j] = v * rinv;
        }
    }

    // Sinv = A^{-1} column by column (all unrolled -> registers)
    float Sinv[DD][DD];
    #pragma unroll
    for (int c = 0; c < DD; ++c) {
        float y[DD], z[DD];
        #pragma unroll
        for (int i = 0; i < DD; ++i) {
            float v = (i == c) ? 1.f : 0.f;
            #pragma unroll
            for (int t = 0; t < i; ++t) v -= L[i][t] * y[t];
            y[i] = v * Dinv[i];
        }
        #pragma unroll
        for (int i = DD - 1; i >= 0; --i) {
            float v = y[i];
            #pragma unroll
            for (int t = i + 1; t < DD; ++t) v -= L[t][i] * z[t];
            z[i] = v * Dinv[i];
        }
        #pragma unroll
        for (int i = 0; i < DD; ++i) Sinv[i][c] = z[i];
    }

    const float* mu = mus + k * DD;
    float smu[DD];
    float cc = 0.f;
    #pragma unroll
    for (int i = 0; i < DD; ++i) {
        float v = 0.f;
        #pragma unroll
        for (int j = 0; j < DD; ++j) v += Sinv[i][j] * mu[j];
        smu[i] = v;
        cc += mu[i] * v;
    }

    // wave-parallel softmax(prior_logits)[k]
    float lg = prior_logits[k];
    float m = lg;
    #pragma unroll
    for (int off = 32; off > 0; off >>= 1)
        m = fmaxf(m, __shfl_xor(m, off, 64));
    float e = EXP2F((lg - m) * LOG2E);
    float se = e;
    #pragma unroll
    for (int off = 32; off > 0; off >>= 1)
        se += __shfl_xor(se, off, 64);
    float lprior = lg - m - LOG2F_FAST(se) * LN2F;

    const float s2 = -0.5f * LOG2E;
    float qw[NPAIR];
    {
        int t = 0;
        #pragma unroll
        for (int i = 0; i < DD; ++i)
            #pragma unroll
            for (int j = i; j < DD; ++j) {
                qw[t] = s2 * Sinv[i][j] * ((i == j) ? 1.f : 2.f);
                ++t;
            }
    }
    const float cconst = LOG2E * (lprior - 4.f * LN2PI) + s2 * (ld2 * LN2F + cc);

    float* w = coefs + k * COEF_STRIDE;
    #pragma unroll
    for (int t = 0; t < NPAIR; ++t) w[t] = qw[t];
    #pragma unroll
    for (int i = 0; i < DD; ++i) w[NPAIR + i] = LOG2E * smu[i];
    w[44] = cconst;
    w[45] = 0.f; w[46] = 0.f; w[47] = 0.f;

    // compact fast-path record (64 B stride)
    float* f = fastc + k * FAST_STRIDE;
    #pragma unroll
    for (int i = 0; i < DD; ++i) f[i] = LOG2E * smu[i];
    f[8] = cconst;
    #pragma unroll
    for (int i = 9; i < FAST_STRIDE; ++i) f[i] = 0.f;

    // all-k quad-block equality check (bitwise; NaN -> flag 0 -> general path)
    int eq = 1;
    #pragma unroll
    for (int t = 0; t < NPAIR; ++t) {
        float l0v = __shfl(qw[t], 0, 64);
        eq &= (qw[t] == l0v) ? 1 : 0;
    }
    unsigned long long b = __ballot(eq != 0);
    if (k == 0) *flag = (b == 0xFFFFFFFFFFFFFFFFULL) ? 1 : 0;
}

// ---------------------------------------------------------------------------
// Main, 8 points/thread.
// Model from R9/R10/R12 A/B/C: coef delivery is a THROUGHPUT toll on whichever
// pipe carries it (LDS 34us / K$ 36us / VALU-readlane 44us). At PT=4 the LDS
// unit (shared per CU, ~12cy per uniform ds_read_b128 incl. 64-lane
// writeback) is the binding resource: 15 waves x 192 reads x 12cy ~ 14us/CU >
// VALU ~10.5us. PT=8 halves LDS-per-FLOP: LDS ~7.7us < VALU ~11-13us ->
// VALU-bound. k-loop stays ROLLED (I$), all arrays statically indexed.
// ---------------------------------------------------------------------------
__global__ __launch_bounds__(BLK) void gmm_main(
    const float* __restrict__ X,
    const float* __restrict__ coefs,
    const float* __restrict__ fastc,
    const int* __restrict__ flag,
    double* __restrict__ acc,
    int* __restrict__ counter,
    float* __restrict__ out)
{
    __shared__ float4 lcoef[KC * 12];   // 12 KB: general path
    __shared__ float4 lfast[KC * 4];    //  4 KB: fast path

    const int pbase = blockIdx.x * PTS_PER_BLK + threadIdx.x;

    float x[PT_PER_TH][DD];
    bool  valid[PT_PER_TH];
    #pragma unroll
    for (int p = 0; p < PT_PER_TH; ++p) {
        const int pi = pbase + p * BLK;
        valid[p] = (pi < N_PTS);
        if (valid[p]) {
            const float4* xp = (const float4*)(X + (size_t)pi * DD);
            float4 a = xp[0], b = xp[1];
            x[p][0]=a.x; x[p][1]=a.y; x[p][2]=a.z; x[p][3]=a.w;
            x[p][4]=b.x; x[p][5]=b.y; x[p][6]=b.z; x[p][7]=b.w;
        } else {
            #pragma unroll
            for (int i = 0; i < DD; ++i) x[p][i] = 0.f;
        }
    }

    double ll = 0.0;

    if (*flag) {
        // ---- fast path: shared quadratic, per-k {V[8],C} from LDS ----
        if (threadIdx.x < KC * 4)
            lfast[threadIdx.x] = ((const float4*)fastc)[threadIdx.x];
        __syncthreads();

        // q = x^T W x (W wave-uniform -> scalar loads, once)
        float q[PT_PER_TH];
        {
            float Q[NPAIR];
            #pragma unroll
            for (int t = 0; t < NPAIR; ++t) Q[t] = coefs[t];
            #pragma unroll
            for (int p = 0; p < PT_PER_TH; ++p) {
                float qq = 0.f;
                int t = 0;
                #pragma unroll
                for (int i = 0; i < DD; ++i) {
                    float s = 0.f;
                    #pragma unroll
                    for (int j = i; j < DD; ++j, ++t)
                        s = fmaf(Q[t], x[p][j], s);
                    qq = fmaf(x[p][i], s, qq);
                }
                q[p] = qq;
            }
        }

        float ss[PT_PER_TH];
        #pragma unroll
        for (int p = 0; p < PT_PER_TH; ++p) ss[p] = 0.f;

        for (int k = 0; k < KC; ++k) {
            const float4* cp = &lfast[k * 4];
            float4 l0 = cp[0], l1 = cp[1], c4 = cp[2];
            #pragma unroll
            for (int p = 0; p < PT_PER_TH; ++p) {
                float a = fmaf(l0.x, x[p][0], c4.x);
                a = fmaf(l0.y, x[p][1], a);
                a = fmaf(l0.z, x[p][2], a);
                a = fmaf(l0.w, x[p][3], a);
                a = fmaf(l1.x, x[p][4], a);
                a = fmaf(l1.y, x[p][5], a);
                a = fmaf(l1.z, x[p][6], a);
                a = fmaf(l1.w, x[p][7], a);
                ss[p] += EXP2F(a);
            }
        }

        #pragma unroll
        for (int p = 0; p < PT_PER_TH; ++p)
            if (valid[p])
                ll += (double)((q[p] + LOG2F_FAST(ss[p])) * LN2F);
    } else {
        // ---- general path: LDS-staged per-k full quadratic ----
        {
            const float4* g = (const float4*)coefs;
            #pragma unroll
            for (int r = 0; r < 3; ++r)
                lcoef[threadIdx.x + r * BLK] = g[threadIdx.x + r * BLK];
        }
        __syncthreads();

        float ss[PT_PER_TH];
        #pragma unroll
        for (int p = 0; p < PT_PER_TH; ++p) ss[p] = 0.f;

        for (int k = 0; k < KC; ++k) {
            float cw[COEF_STRIDE];
            {
                const float4* cp = &lcoef[k * 12];
                #pragma unroll
                for (int r = 0; r < 12; ++r) {
                    float4 c = cp[r];
                    cw[4*r+0] = c.x; cw[4*r+1] = c.y; cw[4*r+2] = c.z; cw[4*r+3] = c.w;
                }
            }
            #pragma unroll
            for (int p = 0; p < PT_PER_TH; ++p) {
                float a = cw[44];
                int t = 0;
                #pragma unroll
                for (int i = 0; i < DD; ++i) {
                    float s = cw[NPAIR + i];
                    #pragma unroll
                    for (int j = i; j < DD; ++j, ++t)
                        s = fmaf(cw[t], x[p][j], s);
                    a = fmaf(x[p][i], s, a);
                }
                ss[p] += EXP2F(a);
            }
        }

        #pragma unroll
        for (int p = 0; p < PT_PER_TH; ++p)
            if (valid[p])
                ll += (double)(LOG2F_FAST(ss[p]) * LN2F);
    }

    // wave(64) shuffle reduce in double
    #pragma unroll
    for (int off = 32; off > 0; off >>= 1)
        ll += __shfl_down(ll, off, 64);

    __shared__ double wsum[BLK / 64];
    const int lane = threadIdx.x & 63;
    const int wid  = threadIdx.x >> 6;
    if (lane == 0) wsum[wid] = ll;
    __syncthreads();
    if (threadIdx.x == 0) {
        double t = 0.0;
        #pragma unroll
        for (int wgi = 0; wgi < BLK / 64; ++wgi) t += wsum[wgi];
        atomicAdd(acc, t);
        __threadfence();
        int old = atomicAdd(counter, 1);
        if (old == NB - 1) {
            __threadfence();
            double v = atomicAdd(acc, 0.0);   // coherent read of the full sum
            out[0] = (float)v;
        }
    }
}

extern "C" void kernel_launch(void* const* d_in, const int* in_sizes, int n_in,
                              void* d_out, int out_size, void* d_ws, size_t ws_size,
                              hipStream_t stream)
{
    const float* X      = (const float*)d_in[0];
    const float* prior  = (const float*)d_in[1];
    const float* mus    = (const float*)d_in[2];
    const float* covraw = (const float*)d_in[3];
    float* out = (float*)d_out;

    double* acc  = (double*)d_ws;
    int* counter = (int*)((char*)d_ws + 128);
    int* flag    = (int*)((char*)d_ws + 132);
    float* coefs = (float*)((char*)d_ws + 256);                  // KC*48*4 = 12288 B
    float* fastc = (float*)((char*)d_ws + 256 + 12544);          // KC*16*4 = 4096 B

    gmm_prep<<<1, 64, 0, stream>>>(prior, mus, covraw, coefs, fastc, acc, counter, flag);
    gmm_main<<<NB, BLK, 0, stream>>>(X, coefs, fastc, flag, acc, counter, out);
}

// Round 15
// 104.881 us; speedup vs baseline: 1.3866x; 1.0052x over previous
//
#include <hip/hip_runtime.h>

#define N_PTS 1000000
#define KC 64
#define DD 8
#define NPAIR 36          // D*(D+1)/2
#define BLK 512
#define PT_PER_TH 8
#define PTS_PER_BLK (BLK * PT_PER_TH)          // 4096
#define NB ((N_PTS + PTS_PER_BLK - 1) / PTS_PER_BLK)   // 245 blocks <= 256 CUs: one round, no tail

#if __has_builtin(__builtin_amdgcn_exp2f)
#define EXP2F(x) __builtin_amdgcn_exp2f(x)
#else
#define EXP2F(x) exp2f(x)
#endif
#if __has_builtin(__builtin_amdgcn_logf)
#define LOG2F_FAST(x) __builtin_amdgcn_logf(x)
#else
#define LOG2F_FAST(x) log2f(x)
#endif
#if __has_builtin(__builtin_amdgcn_rcpf)
#define RCPF(x) __builtin_amdgcn_rcpf(x)
#else
#define RCPF(x) (1.0f / (x))
#endif
#if __has_builtin(__builtin_amdgcn_sqrtf)
#define SQRTF(x) __builtin_amdgcn_sqrtf(x)
#else
#define SQRTF(x) sqrtf(x)
#endif

#define LOG2E 1.44269504088896340736f
#define LN2F  0.69314718055994530942f
#define LN2PI 1.83787706640934548356f

__device__ __forceinline__ float fast_tanh(float x) {
    float cl = fminf(fmaxf(x, -15.f), 15.f);
    float e = EXP2F(cl * (2.f * LOG2E));      // e^(2x)
    return (e - 1.f) * RCPF(e + 1.f);
}

__global__ void gmm_init(double* __restrict__ acc, int* __restrict__ counter) {
    *acc = 0.0;
    *counter = 0;
}

// ---------------------------------------------------------------------------
// Fused kernel. Per block:
//   phase 1 (threads 0..63 = wave 0): full prep (cov build, Cholesky, inverse,
//     det, softmax prior) straight into LDS — no prep kernel, no global coef
//     round-trip. ~1-2 us, one round across <=1 block/CU. Fully unrolled
//     (rule #20: compile-time indices -> VGPRs).
//   phase 2 (all 8 waves): 8 points/thread. Fast path (flag: quad block
//     identical across k): q = x^T W x once, then per k {V[8],C} from LDS,
//     9 FMA + exp2; ll = ln2*(q + log2 sum). General path: full per-k quad.
//   epilogue: block double-reduce -> atomicAdd; last block (completion
//     counter) writes out.
// Geometry: 245 blocks -> every CU gets <=1 block (no 2-round tail imbalance,
// the R13 suspect for the invariant ~35us main).
// ---------------------------------------------------------------------------
__global__ __launch_bounds__(BLK, 2) void gmm_fused(
    const float* __restrict__ X,
    const float* __restrict__ prior_logits,
    const float* __restrict__ mus,
    const float* __restrict__ cov_raw,
    double* __restrict__ acc,
    int* __restrict__ counter,
    float* __restrict__ out)
{
    __shared__ float4 lcoef[KC * 12];   // 12 KB: full records (general path; row0 = W for fast path)
    __shared__ float4 lfast[KC * 4];    //  4 KB: {V[8], C, pad} per k (fast path)
    __shared__ int    sflag;
    __shared__ double wsum[BLK / 64];

    const int tid = threadIdx.x;

    // ---------------- phase 1: in-block prep (wave 0) ----------------
    if (tid < KC) {
        const int k = tid;
        const float* raw = cov_raw + k * DD * DD;
        float A[DD][DD];
        #pragma unroll
        for (int i = 0; i < DD; ++i)
            #pragma unroll
            for (int j = 0; j < DD; ++j)
                A[i][j] = (i == j) ? EXP2F(raw[i * DD + i] * LOG2E)
                                   : fast_tanh(0.5f * (raw[i * DD + j] + raw[j * DD + i]));

        float L[DD][DD], Dinv[DD];
        float ld2 = 0.f;  // log2(det)
        #pragma unroll
        for (int j = 0; j < DD; ++j) {
            float s = A[j][j];
            #pragma unroll
            for (int t = 0; t < j; ++t) s -= L[j][t] * L[j][t];
            float ljj = SQRTF(s);
            L[j][j] = ljj;
            float rinv = RCPF(ljj);
            Dinv[j] = rinv;
            ld2 += 2.f * LOG2F_FAST(ljj);
            #pragma unroll
            for (int i = j + 1; i < DD; ++i) {
                float v = A[i][j];
                #pragma unroll
                for (int t = 0; t < j; ++t) v -= L[i][t] * L[j][t];
                L[i][j] = v * rinv;
            }
        }

        float Sinv[DD][DD];
        #pragma unroll
        for (int c = 0; c < DD; ++c) {
            float y[DD], z[DD];
            #pragma unroll
            for (int i = 0; i < DD; ++i) {
                float v = (i == c) ? 1.f : 0.f;
                #pragma unroll
                for (int t = 0; t < i; ++t) v -= L[i][t] * y[t];
                y[i] = v * Dinv[i];
            }
            #pragma unroll
            for (int i = DD - 1; i >= 0; --i) {
                float v = y[i];
                #pragma unroll
                for (int t = i + 1; t < DD; ++t) v -= L[t][i] * z[t];
                z[i] = v * Dinv[i];
            }
            #pragma unroll
            for (int i = 0; i < DD; ++i) Sinv[i][c] = z[i];
        }

        const float* mu = mus + k * DD;
        float smu[DD];
        float cc = 0.f;
        #pragma unroll
        for (int i = 0; i < DD; ++i) {
            float v = 0.f;
            #pragma unroll
            for (int j = 0; j < DD; ++j) v += Sinv[i][j] * mu[j];
            smu[i] = v;
            cc += mu[i] * v;
        }

        // wave-parallel softmax(prior_logits)[k] within wave 0
        float lg = prior_logits[k];
        float m = lg;
        #pragma unroll
        for (int off = 32; off > 0; off >>= 1)
            m = fmaxf(m, __shfl_xor(m, off, 64));
        float e = EXP2F((lg - m) * LOG2E);
        float se = e;
        #pragma unroll
        for (int off = 32; off > 0; off >>= 1)
            se += __shfl_xor(se, off, 64);
        float lprior = lg - m - LOG2F_FAST(se) * LN2F;

        const float s2 = -0.5f * LOG2E;
        float qw[NPAIR];
        {
            int t = 0;
            #pragma unroll
            for (int i = 0; i < DD; ++i)
                #pragma unroll
                for (int j = i; j < DD; ++j) {
                    qw[t] = s2 * Sinv[i][j] * ((i == j) ? 1.f : 2.f);
                    ++t;
                }
        }
        const float cconst = LOG2E * (lprior - 4.f * LN2PI) + s2 * (ld2 * LN2F + cc);

        float* w = (float*)lcoef + k * 48;
        #pragma unroll
        for (int t = 0; t < NPAIR; ++t) w[t] = qw[t];
        #pragma unroll
        for (int i = 0; i < DD; ++i) w[NPAIR + i] = LOG2E * smu[i];
        w[44] = cconst;
        w[45] = 0.f; w[46] = 0.f; w[47] = 0.f;

        float* f = (float*)lfast + k * 16;
        #pragma unroll
        for (int i = 0; i < DD; ++i) f[i] = LOG2E * smu[i];
        f[8] = cconst;
        #pragma unroll
        for (int i = 9; i < 16; ++i) f[i] = 0.f;

        // quad-block equality across k (bitwise; NaN -> general path)
        int eq = 1;
        #pragma unroll
        for (int t = 0; t < NPAIR; ++t) {
            float l0v = __shfl(qw[t], 0, 64);
            eq &= (qw[t] == l0v) ? 1 : 0;
        }
        unsigned long long b = __ballot(eq != 0);
        if (k == 0) sflag = (b == 0xFFFFFFFFFFFFFFFFULL) ? 1 : 0;
    }
    __syncthreads();

    // ---------------- phase 2: point loop ----------------
    const int pbase = blockIdx.x * PTS_PER_BLK + tid;

    float x[PT_PER_TH][DD];
    bool  valid[PT_PER_TH];
    #pragma unroll
    for (int p = 0; p < PT_PER_TH; ++p) {
        const int pi = pbase + p * BLK;
        valid[p] = (pi < N_PTS);
        if (valid[p]) {
            const float4* xp = (const float4*)(X + (size_t)pi * DD);
            float4 a = xp[0], b = xp[1];
            x[p][0]=a.x; x[p][1]=a.y; x[p][2]=a.z; x[p][3]=a.w;
            x[p][4]=b.x; x[p][5]=b.y; x[p][6]=b.z; x[p][7]=b.w;
        } else {
            #pragma unroll
            for (int i = 0; i < DD; ++i) x[p][i] = 0.f;
        }
    }

    double ll = 0.0;

    if (sflag) {
        // ---- fast path ----
        float q[PT_PER_TH];
        {
            float Q[NPAIR];
            const float* Qs = (const float*)lcoef;   // component 0's W (uniform addr)
            #pragma unroll
            for (int t = 0; t < NPAIR; ++t) Q[t] = Qs[t];
            #pragma unroll
            for (int p = 0; p < PT_PER_TH; ++p) {
                float qq = 0.f;
                int t = 0;
                #pragma unroll
                for (int i = 0; i < DD; ++i) {
                    float s = 0.f;
                    #pragma unroll
                    for (int j = i; j < DD; ++j, ++t)
                        s = fmaf(Q[t], x[p][j], s);
                    qq = fmaf(x[p][i], s, qq);
                }
                q[p] = qq;
            }
        }

        float ss[PT_PER_TH];
        #pragma unroll
        for (int p = 0; p < PT_PER_TH; ++p) ss[p] = 0.f;

        for (int k = 0; k < KC; ++k) {
            const float4* cp = &lfast[k * 4];
            float4 l0 = cp[0], l1 = cp[1], c4 = cp[2];
            #pragma unroll
            for (int p = 0; p < PT_PER_TH; ++p) {
                float a = fmaf(l0.x, x[p][0], c4.x);
                a = fmaf(l0.y, x[p][1], a);
                a = fmaf(l0.z, x[p][2], a);
                a = fmaf(l0.w, x[p][3], a);
                a = fmaf(l1.x, x[p][4], a);
                a = fmaf(l1.y, x[p][5], a);
                a = fmaf(l1.z, x[p][6], a);
                a = fmaf(l1.w, x[p][7], a);
                ss[p] += EXP2F(a);
            }
        }

        #pragma unroll
        for (int p = 0; p < PT_PER_TH; ++p)
            if (valid[p])
                ll += (double)((q[p] + LOG2F_FAST(ss[p])) * LN2F);
    } else {
        // ---- general path: per-k full quadratic from LDS ----
        float ss[PT_PER_TH];
        #pragma unroll
        for (int p = 0; p < PT_PER_TH; ++p) ss[p] = 0.f;

        for (int k = 0; k < KC; ++k) {
            float cw[48];
            {
                const float4* cp = &lcoef[k * 12];
                #pragma unroll
                for (int r = 0; r < 12; ++r) {
                    float4 c = cp[r];
                    cw[4*r+0] = c.x; cw[4*r+1] = c.y; cw[4*r+2] = c.z; cw[4*r+3] = c.w;
                }
            }
            #pragma unroll
            for (int p = 0; p < PT_PER_TH; ++p) {
                float a = cw[44];
                int t = 0;
                #pragma unroll
                for (int i = 0; i < DD; ++i) {
                    float s = cw[NPAIR + i];
                    #pragma unroll
                    for (int j = i; j < DD; ++j, ++t)
                        s = fmaf(cw[t], x[p][j], s);
                    a = fmaf(x[p][i], s, a);
                }
                ss[p] += EXP2F(a);
            }
        }

        #pragma unroll
        for (int p = 0; p < PT_PER_TH; ++p)
            if (valid[p])
                ll += (double)(LOG2F_FAST(ss[p]) * LN2F);
    }

    // ---------------- epilogue: reduce + completion ----------------
    #pragma unroll
    for (int off = 32; off > 0; off >>= 1)
        ll += __shfl_down(ll, off, 64);

    const int lane = tid & 63;
    const int wid  = tid >> 6;
    if (lane == 0) wsum[wid] = ll;
    __syncthreads();
    if (tid == 0) {
        double t = 0.0;
        #pragma unroll
        for (int wgi = 0; wgi < BLK / 64; ++wgi) t += wsum[wgi];
        atomicAdd(acc, t);
        __threadfence();
        int old = atomicAdd(counter, 1);
        if (old == NB - 1) {
            __threadfence();
            double v = atomicAdd(acc, 0.0);   // coherent read of the full sum
            out[0] = (float)v;
        }
    }
}

extern "C" void kernel_launch(void* const* d_in, const int* in_sizes, int n_in,
                              void* d_out, int out_size, void* d_ws, size_t ws_size,
                              hipStream_t stream)
{
    const float* X      = (const float*)d_in[0];
    const float* prior  = (const float*)d_in[1];
    const float* mus    = (const float*)d_in[2];
    const float* covraw = (const float*)d_in[3];
    float* out = (float*)d_out;

    double* acc  = (double*)d_ws;
    int* counter = (int*)((char*)d_ws + 128);

    gmm_init<<<1, 1, 0, stream>>>(acc, counter);
    gmm_fused<<<NB, BLK, 0, stream>>>(X, prior, mus, covraw, acc, counter, out);
}